// Round 7
// baseline (324.903 us; speedup 1.0000x reference)
//
#include <hip/hip_runtime.h>
#include <hip/hip_fp16.h>
#include <math.h>

typedef __attribute__((ext_vector_type(8))) _Float16 half8;
typedef __attribute__((ext_vector_type(2))) __fp16 fp16x2;   // cvt_pkrtz result type
typedef __attribute__((ext_vector_type(4))) float float4v;
typedef __attribute__((ext_vector_type(2))) float float2v;

#define MFMA_F16 __builtin_amdgcn_mfma_f32_16x16x32_f16

// ws layout (bytes), written by prepack_kernel each launch:
//   [0, 8192)     bfr table: [lane][nt][kh] half8  at lane*128 + nt*32 + kh*16
//   [8192, 9216)  per-lg (256B): w1 pairs [kh][d][p] at kh*96+d*32+p*8 ; b1 pairs at 192+kh*32+p*8
//   [9216, 9728)  per-lg (128B): b2v[nt] float4 at nt*16 ; w3v[nt] at 64+nt*16
__global__ void prepack_kernel(const float* __restrict__ W1, const float* __restrict__ b1,
                               const float* __restrict__ W2, const float* __restrict__ b2,
                               const float* __restrict__ W3, char* __restrict__ ws)
{
    const int lane = threadIdx.x & 63;
    const int lg = lane >> 4, lr = lane & 15;
    // W2^T A-fragments, identical cvt_pkrtz math to the verified in-kernel build
    #pragma unroll
    for (int nt = 0; nt < 4; ++nt) {
        #pragma unroll
        for (int kh = 0; kh < 2; ++kh) {
            union { fp16x2 h2[4]; half8 h8; } u;
            #pragma unroll
            for (int ep = 0; ep < 4; ++ep) {
                const int k0 = kh * 32 + lg * 8 + ep * 2;
                u.h2[ep] = __builtin_amdgcn_cvt_pkrtz(W2[k0 * 64 + nt * 16 + lr],
                                                      W2[(k0 + 1) * 64 + nt * 16 + lr]);
            }
            *(half8*)(ws + lane * 128 + nt * 32 + kh * 16) = u.h8;
        }
    }
    if (lane < 4) {                       // w1/b1 pairs for lg = lane
        char* base = ws + 8192 + lane * 256;
        #pragma unroll
        for (int kh = 0; kh < 2; ++kh) {
            #pragma unroll
            for (int p = 0; p < 4; ++p) {
                const int h = kh * 32 + lane * 8 + 2 * p;
                #pragma unroll
                for (int d = 0; d < 3; ++d) {
                    float2v w = {W1[d * 64 + h], W1[d * 64 + h + 1]};
                    *(float2v*)(base + kh * 96 + d * 32 + p * 8) = w;
                }
                float2v bb = {b1[h], b1[h + 1]};
                *(float2v*)(base + 192 + kh * 32 + p * 8) = bb;
            }
        }
    } else if (lane >= 8 && lane < 12) {  // b2/w3 vectors for lg = lane-8
        const int lgx = lane - 8;
        char* base = ws + 9216 + lgx * 128;
        #pragma unroll
        for (int nt = 0; nt < 4; ++nt) {
            const int h0 = nt * 16 + lgx * 4;
            float4v bv = {b2[h0], b2[h0 + 1], b2[h0 + 2], b2[h0 + 3]};
            *(float4v*)(base + nt * 16) = bv;
            float4v w3_ = {W3[h0], W3[h0 + 1], W3[h0 + 2], W3[h0 + 3]};
            *(float4v*)(base + 64 + nt * 16) = w3_;
        }
    }
}

// One wave per (m,n1) row; 4 waves/block; grid 1024. Per wave: 64 tiles of 16
// points. Layer1 packed fp32 -> fp16 B-frags; layer2 swapped MFMA (A=W2^T);
// layer3 packed relu-dot + 2 shfl; wave-private softmax. Weights from ws.
__global__ __launch_bounds__(256, 4) void mlp_softmax_kernel(
    const float* __restrict__ diff, const int* __restrict__ mask,
    const char* __restrict__ ws, float* __restrict__ out)
{
    __shared__ float s_dots[4][1024];
    __shared__ char  s_tab[1536];

    const int tid = threadIdx.x;
    if (tid < 96) ((float4v*)s_tab)[tid] = ((const float4v*)(ws + 8192))[tid];
    __syncthreads();

    const int lane = tid & 63, wv = tid >> 6;
    const int lg = lane >> 4,  lr = lane & 15;
    const int row = blockIdx.x * 4 + wv;

    half8 bfr[4][2];
    #pragma unroll
    for (int nt = 0; nt < 4; ++nt)
        #pragma unroll
        for (int kh = 0; kh < 2; ++kh)
            bfr[nt][kh] = *(const half8*)(ws + lane * 128 + nt * 32 + kh * 16);

    const char* tb = s_tab + lg * 256;
    float2v w1p[2][3][4], b1p[2][4];
    #pragma unroll
    for (int kh = 0; kh < 2; ++kh) {
        #pragma unroll
        for (int p = 0; p < 4; ++p) {
            #pragma unroll
            for (int d = 0; d < 3; ++d)
                w1p[kh][d][p] = *(const float2v*)(tb + kh * 96 + d * 32 + p * 8);
            b1p[kh][p] = *(const float2v*)(tb + 192 + kh * 32 + p * 8);
        }
    }
    const char* tc = s_tab + 1024 + lg * 128;
    float4v b2v[4], w3v[4];
    #pragma unroll
    for (int nt = 0; nt < 4; ++nt) {
        b2v[nt] = *(const float4v*)(tc + nt * 16);
        w3v[nt] = *(const float4v*)(tc + 64 + nt * 16);
    }

    const float* drow = diff + (long)row * 3072;
    const float2v zero2 = {0.0f, 0.0f};
    const float4v zero4 = {0.0f, 0.0f, 0.0f, 0.0f};

    #pragma unroll 2
    for (int t = 0; t < 64; ++t) {
        const int jp = t * 16 + lr;
        const float x0 = drow[jp * 3 + 0];
        const float x1 = drow[jp * 3 + 1];
        const float x2 = drow[jp * 3 + 2];
        const float2v x0p = {x0, x0}, x1p = {x1, x1}, x2p = {x2, x2};

        half8 afr[2];
        #pragma unroll
        for (int kh = 0; kh < 2; ++kh) {
            union { fp16x2 h2[4]; half8 h8; } u;
            #pragma unroll
            for (int p = 0; p < 4; ++p) {
                float2v h = b1p[kh][p];
                h = __builtin_elementwise_fma(x0p, w1p[kh][0][p], h);
                h = __builtin_elementwise_fma(x1p, w1p[kh][1][p], h);
                h = __builtin_elementwise_fma(x2p, w1p[kh][2][p], h);
                h = __builtin_elementwise_max(h, zero2);
                u.h2[p] = __builtin_amdgcn_cvt_pkrtz(h[0], h[1]);
            }
            afr[kh] = u.h8;
        }

        float2v sr2 = zero2;
        #pragma unroll
        for (int nt = 0; nt < 4; ++nt) {
            float4v acc = b2v[nt];                             // bias via C-in
            acc = MFMA_F16(bfr[nt][0], afr[0], acc, 0, 0, 0);  // A=W2^T, B=h1
            acc = MFMA_F16(bfr[nt][1], afr[1], acc, 0, 0, 0);
            const float4v rl = __builtin_elementwise_max(acc, zero4);
            const float2v rlo = {rl[0], rl[1]}, rhi = {rl[2], rl[3]};
            const float2v wlo = {w3v[nt][0], w3v[nt][1]};
            const float2v whi = {w3v[nt][2], w3v[nt][3]};
            sr2 = __builtin_elementwise_fma(rlo, wlo, sr2);
            sr2 = __builtin_elementwise_fma(rhi, whi, sr2);
        }
        float sr = sr2[0] + sr2[1];
        sr += __shfl_xor(sr, 16, 64);
        sr += __shfl_xor(sr, 32, 64);
        if (lane < 16) s_dots[wv][t * 16 + lane] = sr;
    }
    __syncthreads();   // also orders the cross-lane LDS RAW within each wave

    // ---- wave-private masked softmax over this row's 1024 points ----
    const int* mrow = mask + (long)row * 1024;
    float d[16];
    #pragma unroll
    for (int i = 0; i < 16; ++i) {
        const int p = lane + 64 * i;
        const int mv = mrow[p];
        d[i] = mv ? -__builtin_inff() : s_dots[wv][p];
    }
    float mx = d[0];
    #pragma unroll
    for (int i = 1; i < 16; ++i) mx = fmaxf(mx, d[i]);
    #pragma unroll
    for (int off = 1; off < 64; off <<= 1) mx = fmaxf(mx, __shfl_xor(mx, off, 64));
    float s = 0.0f;
    #pragma unroll
    for (int i = 0; i < 16; ++i) { d[i] = __expf(d[i] - mx); s += d[i]; }  // exp(-inf)=0
    #pragma unroll
    for (int off = 1; off < 64; off <<= 1) s += __shfl_xor(s, off, 64);
    const float inv = 1.0f / s;
    float* orow = out + (long)row * 1024;
    #pragma unroll
    for (int i = 0; i < 16; ++i) orow[lane + 64 * i] = d[i] * inv;
}

extern "C" void kernel_launch(void* const* d_in, const int* in_sizes, int n_in,
                              void* d_out, int out_size, void* d_ws, size_t ws_size,
                              hipStream_t stream) {
    const float* diff = (const float*)d_in[0];
    const int*   mask = (const int*)d_in[1];
    const float* W1   = (const float*)d_in[2];
    const float* b1   = (const float*)d_in[3];
    const float* W2   = (const float*)d_in[4];
    const float* b2   = (const float*)d_in[5];
    const float* W3   = (const float*)d_in[6];
    // b3 (d_in[7]) cancels in softmax -> unused
    float* out = (float*)d_out;
    char*  ws  = (char*)d_ws;   // needs ~9.7 KB

    prepack_kernel<<<dim3(1), dim3(64), 0, stream>>>(W1, b1, W2, b2, W3, ws);
    mlp_softmax_kernel<<<dim3(1024), dim3(256), 0, stream>>>(diff, mask, ws, out);
}

// Round 8
// 318.807 us; speedup vs baseline: 1.0191x; 1.0191x over previous
//
#include <hip/hip_runtime.h>
#include <hip/hip_fp16.h>
#include <math.h>

typedef __attribute__((ext_vector_type(8))) _Float16 half8;
typedef __attribute__((ext_vector_type(2))) __fp16 fp16x2;   // cvt_pkrtz result type
typedef __attribute__((ext_vector_type(4))) float float4v;
typedef __attribute__((ext_vector_type(2))) float float2v;

#define MFMA_F16 __builtin_amdgcn_mfma_f32_16x16x32_f16

// ws layout (bytes), written by prepack_kernel each launch:
//   [0, 8192)     bfr table: [lane][nt][kh] half8  at lane*128 + nt*32 + kh*16
//   [8192, 9216)  per-lg (256B): w1 pairs [kh][d][p] at kh*96+d*32+p*8 ; b1 pairs at 192+kh*32+p*8
//   [9216, 9728)  per-lg (128B): b2v[nt] float4 at nt*16 ; w3v[nt] at 64+nt*16
__global__ void prepack_kernel(const float* __restrict__ W1, const float* __restrict__ b1,
                               const float* __restrict__ W2, const float* __restrict__ b2,
                               const float* __restrict__ W3, char* __restrict__ ws)
{
    const int lane = threadIdx.x & 63;
    const int lg = lane >> 4, lr = lane & 15;
    #pragma unroll
    for (int nt = 0; nt < 4; ++nt) {
        #pragma unroll
        for (int kh = 0; kh < 2; ++kh) {
            union { fp16x2 h2[4]; half8 h8; } u;
            #pragma unroll
            for (int ep = 0; ep < 4; ++ep) {
                const int k0 = kh * 32 + lg * 8 + ep * 2;
                u.h2[ep] = __builtin_amdgcn_cvt_pkrtz(W2[k0 * 64 + nt * 16 + lr],
                                                      W2[(k0 + 1) * 64 + nt * 16 + lr]);
            }
            *(half8*)(ws + lane * 128 + nt * 32 + kh * 16) = u.h8;
        }
    }
    if (lane < 4) {                       // w1/b1 pairs for lg = lane
        char* base = ws + 8192 + lane * 256;
        #pragma unroll
        for (int kh = 0; kh < 2; ++kh) {
            #pragma unroll
            for (int p = 0; p < 4; ++p) {
                const int h = kh * 32 + lane * 8 + 2 * p;
                #pragma unroll
                for (int d = 0; d < 3; ++d) {
                    float2v w = {W1[d * 64 + h], W1[d * 64 + h + 1]};
                    *(float2v*)(base + kh * 96 + d * 32 + p * 8) = w;
                }
                float2v bb = {b1[h], b1[h + 1]};
                *(float2v*)(base + 192 + kh * 32 + p * 8) = bb;
            }
        }
    } else if (lane >= 8 && lane < 12) {  // b2/w3 vectors for lg = lane-8
        const int lgx = lane - 8;
        char* base = ws + 9216 + lgx * 128;
        #pragma unroll
        for (int nt = 0; nt < 4; ++nt) {
            const int h0 = nt * 16 + lgx * 4;
            float4v bv = {b2[h0], b2[h0 + 1], b2[h0 + 2], b2[h0 + 3]};
            *(float4v*)(base + nt * 16) = bv;
            float4v w3_ = {W3[h0], W3[h0 + 1], W3[h0 + 2], W3[h0 + 3]};
            *(float4v*)(base + 64 + nt * 16) = w3_;
        }
    }
}

// One block per (m, n1) row: 1024 points. 4 waves; each wave owns 256 points
// in 16 tiles of 16. diff row staged to LDS with coalesced float4 (round-6
// structure); weight fragments from prepack ws (round-7) -> no per-block
// fragment rebuild, no column-strided LDS reads.
__global__ __launch_bounds__(256, 4) void mlp_softmax_kernel(
    const float* __restrict__ diff, const int* __restrict__ mask,
    const char* __restrict__ ws, float* __restrict__ out)
{
    __shared__ float s_diff[3072];   // 1024 points x 3 (12 KB)
    __shared__ float s_dots[1024];   // 4 KB
    __shared__ char  s_tab[1536];    // w1/b1 + b2/w3 tables
    __shared__ float s_red[8];

    const int tid = threadIdx.x;
    const int bid = blockIdx.x;                  // m*1024 + n1
    const long row_off = (long)bid * 3072;

    // ---- stage diff row (coalesced float4) + weight tables ----
    {
        const float4v* gd = (const float4v*)(diff + row_off);
        float4v* sd = (float4v*)s_diff;
        #pragma unroll
        for (int it = 0; it < 3; ++it) sd[tid + 256 * it] = gd[tid + 256 * it];
        if (tid < 96) ((float4v*)s_tab)[tid] = ((const float4v*)(ws + 8192))[tid];
    }

    const int lane = tid & 63, wv = tid >> 6;
    const int lg = lane >> 4,  lr = lane & 15;

    // prepacked W2^T A-fragments straight from global (L2-hit after block 0)
    half8 bfr[4][2];
    #pragma unroll
    for (int nt = 0; nt < 4; ++nt)
        #pragma unroll
        for (int kh = 0; kh < 2; ++kh)
            bfr[nt][kh] = *(const half8*)(ws + lane * 128 + nt * 32 + kh * 16);

    __syncthreads();

    const char* tb = s_tab + lg * 256;
    float2v w1p[2][3][4], b1p[2][4];
    #pragma unroll
    for (int kh = 0; kh < 2; ++kh) {
        #pragma unroll
        for (int p = 0; p < 4; ++p) {
            #pragma unroll
            for (int d = 0; d < 3; ++d)
                w1p[kh][d][p] = *(const float2v*)(tb + kh * 96 + d * 32 + p * 8);
            b1p[kh][p] = *(const float2v*)(tb + 192 + kh * 32 + p * 8);
        }
    }
    const char* tc = s_tab + 1024 + lg * 128;
    float4v b2v[4], w3v[4];
    #pragma unroll
    for (int nt = 0; nt < 4; ++nt) {
        b2v[nt] = *(const float4v*)(tc + nt * 16);
        w3v[nt] = *(const float4v*)(tc + 64 + nt * 16);
    }

    const float2v zero2 = {0.0f, 0.0f};
    const float4v zero4 = {0.0f, 0.0f, 0.0f, 0.0f};

    // ---- main loop: 16 tiles of 16 points per wave ----
    const int jw0 = wv * 256;
    for (int t = 0; t < 16; ++t) {
        const int j0 = jw0 + t * 16;
        const int jp = j0 + lr;                 // this lane's point (B-col)
        const float x0 = s_diff[jp * 3 + 0];
        const float x1 = s_diff[jp * 3 + 1];
        const float x2 = s_diff[jp * 3 + 2];
        const float2v x0p = {x0, x0}, x1p = {x1, x1}, x2p = {x2, x2};

        half8 afr[2];
        #pragma unroll
        for (int kh = 0; kh < 2; ++kh) {
            union { fp16x2 h2[4]; half8 h8; } u;
            #pragma unroll
            for (int p = 0; p < 4; ++p) {
                float2v h = b1p[kh][p];
                h = __builtin_elementwise_fma(x0p, w1p[kh][0][p], h);
                h = __builtin_elementwise_fma(x1p, w1p[kh][1][p], h);
                h = __builtin_elementwise_fma(x2p, w1p[kh][2][p], h);
                h = __builtin_elementwise_max(h, zero2);
                u.h2[p] = __builtin_amdgcn_cvt_pkrtz(h[0], h[1]);
            }
            afr[kh] = u.h8;
        }

        float2v sr2 = zero2;
        #pragma unroll
        for (int nt = 0; nt < 4; ++nt) {
            float4v acc = b2v[nt];                             // bias via C-in
            acc = MFMA_F16(bfr[nt][0], afr[0], acc, 0, 0, 0);  // A=W2^T, B=h1
            acc = MFMA_F16(bfr[nt][1], afr[1], acc, 0, 0, 0);
            const float4v rl = __builtin_elementwise_max(acc, zero4);
            const float2v rlo = {rl[0], rl[1]}, rhi = {rl[2], rl[3]};
            const float2v wlo = {w3v[nt][0], w3v[nt][1]};
            const float2v whi = {w3v[nt][2], w3v[nt][3]};
            sr2 = __builtin_elementwise_fma(rlo, wlo, sr2);
            sr2 = __builtin_elementwise_fma(rhi, whi, sr2);
        }
        float sr = sr2[0] + sr2[1];
        sr += __shfl_xor(sr, 16, 64);
        sr += __shfl_xor(sr, 32, 64);
        if (lane < 16) s_dots[j0 + lane] = sr;
    }
    __syncthreads();

    // ---- masked softmax over the 1024 points (block-wide, tid*4) ----
    const int j4 = tid * 4;
    float4v dv = *(const float4v*)&s_dots[j4];
    const int4 mv = *(const int4*)(mask + (long)bid * 1024 + j4);
    const float NINF = -__builtin_inff();
    float d0 = mv.x ? NINF : dv[0];
    float d1 = mv.y ? NINF : dv[1];
    float d2 = mv.z ? NINF : dv[2];
    float d3 = mv.w ? NINF : dv[3];

    float mx = fmaxf(fmaxf(d0, d1), fmaxf(d2, d3));
    #pragma unroll
    for (int off = 1; off < 64; off <<= 1) mx = fmaxf(mx, __shfl_xor(mx, off, 64));
    if (lane == 0) s_red[wv] = mx;
    __syncthreads();
    mx = fmaxf(fmaxf(s_red[0], s_red[1]), fmaxf(s_red[2], s_red[3]));

    const float e0 = mv.x ? 0.0f : __expf(d0 - mx);
    const float e1 = mv.y ? 0.0f : __expf(d1 - mx);
    const float e2 = mv.z ? 0.0f : __expf(d2 - mx);
    const float e3 = mv.w ? 0.0f : __expf(d3 - mx);
    float s = (e0 + e1) + (e2 + e3);
    #pragma unroll
    for (int off = 1; off < 64; off <<= 1) s += __shfl_xor(s, off, 64);
    if (lane == 0) s_red[4 + wv] = s;
    __syncthreads();
    const float tot = (s_red[4] + s_red[5]) + (s_red[6] + s_red[7]);
    const float inv = 1.0f / tot;

    float4v ov = {e0 * inv, e1 * inv, e2 * inv, e3 * inv};
    *(float4v*)(out + (long)bid * 1024 + j4) = ov;
}

extern "C" void kernel_launch(void* const* d_in, const int* in_sizes, int n_in,
                              void* d_out, int out_size, void* d_ws, size_t ws_size,
                              hipStream_t stream) {
    const float* diff = (const float*)d_in[0];
    const int*   mask = (const int*)d_in[1];
    const float* W1   = (const float*)d_in[2];
    const float* b1   = (const float*)d_in[3];
    const float* W2   = (const float*)d_in[4];
    const float* b2   = (const float*)d_in[5];
    const float* W3   = (const float*)d_in[6];
    // b3 (d_in[7]) cancels in softmax -> unused
    float* out = (float*)d_out;
    char*  ws  = (char*)d_ws;   // needs ~9.7 KB

    prepack_kernel<<<dim3(1), dim3(64), 0, stream>>>(W1, b1, W2, b2, W3, ws);
    mlp_softmax_kernel<<<dim3(4096), dim3(256), 0, stream>>>(diff, mask, ws, out);
}

// Round 10
// 311.832 us; speedup vs baseline: 1.0419x; 1.0224x over previous
//
#include <hip/hip_runtime.h>
#include <hip/hip_fp16.h>
#include <math.h>

typedef __attribute__((ext_vector_type(8))) _Float16 half8;
typedef __attribute__((ext_vector_type(2))) __fp16 fp16x2;   // cvt_pkrtz result type
typedef __attribute__((ext_vector_type(4))) float float4v;
typedef __attribute__((ext_vector_type(2))) float float2v;

#define MFMA_F16 __builtin_amdgcn_mfma_f32_16x16x32_f16

// ws layout (bytes), written by prepack_kernel each launch:
//   [0, 8192)     bfr table: [lane][nt][kh] half8  at lane*128 + nt*32 + kh*16
//   [8192, 9216)  per-lg (256B): w1 pairs [kh][d][p] at kh*96+d*32+p*8 ; b1 pairs at 192+kh*32+p*8
//   [9216, 9728)  per-lg (128B): b2v[nt] float4 at nt*16 ; w3v[nt] at 64+nt*16
__global__ void prepack_kernel(const float* __restrict__ W1, const float* __restrict__ b1,
                               const float* __restrict__ W2, const float* __restrict__ b2,
                               const float* __restrict__ W3, char* __restrict__ ws)
{
    const int lane = threadIdx.x & 63;
    const int lg = lane >> 4, lr = lane & 15;
    #pragma unroll
    for (int nt = 0; nt < 4; ++nt) {
        #pragma unroll
        for (int kh = 0; kh < 2; ++kh) {
            union { fp16x2 h2[4]; half8 h8; } u;
            #pragma unroll
            for (int ep = 0; ep < 4; ++ep) {
                const int k0 = kh * 32 + lg * 8 + ep * 2;
                u.h2[ep] = __builtin_amdgcn_cvt_pkrtz(W2[k0 * 64 + nt * 16 + lr],
                                                      W2[(k0 + 1) * 64 + nt * 16 + lr]);
            }
            *(half8*)(ws + lane * 128 + nt * 32 + kh * 16) = u.h8;
        }
    }
    if (lane < 4) {                       // w1/b1 pairs for lg = lane
        char* base = ws + 8192 + lane * 256;
        #pragma unroll
        for (int kh = 0; kh < 2; ++kh) {
            #pragma unroll
            for (int p = 0; p < 4; ++p) {
                const int h = kh * 32 + lane * 8 + 2 * p;
                #pragma unroll
                for (int d = 0; d < 3; ++d) {
                    float2v w = {W1[d * 64 + h], W1[d * 64 + h + 1]};
                    *(float2v*)(base + kh * 96 + d * 32 + p * 8) = w;
                }
                float2v bb = {b1[h], b1[h + 1]};
                *(float2v*)(base + 192 + kh * 32 + p * 8) = bb;
            }
        }
    } else if (lane >= 8 && lane < 12) {  // b2/w3 vectors for lg = lane-8
        const int lgx = lane - 8;
        char* base = ws + 9216 + lgx * 128;
        #pragma unroll
        for (int nt = 0; nt < 4; ++nt) {
            const int h0 = nt * 16 + lgx * 4;
            float4v bv = {b2[h0], b2[h0 + 1], b2[h0 + 2], b2[h0 + 3]};
            *(float4v*)(base + nt * 16) = bv;
            float4v w3_ = {W3[h0], W3[h0 + 1], W3[h0 + 2], W3[h0 + 3]};
            *(float4v*)(base + 64 + nt * 16) = w3_;
        }
    }
}

// One block per (m, n1) row: 1024 points. 4 waves; each wave owns 256 points
// in 16 tiles of 16. diff row staged to LDS coalesced; ALL weight tables
// LDS-resident (so register shedding remats via ds_read, never scratch).
// bfr fragments live at stride 144 B/lane -> ds_read_b128 is 2-way = free.
// waves_per_eu pinned to 4 so the compiler allocates up to 128 VGPRs.
__global__ __attribute__((amdgpu_flat_work_group_size(256, 256),
                          amdgpu_waves_per_eu(4, 4)))
void mlp_softmax_kernel(
    const float* __restrict__ diff, const int* __restrict__ mask,
    const char* __restrict__ ws, float* __restrict__ out)
{
    __shared__ float s_diff[3072];   // 12 KB: 1024 points x 3
    __shared__ float s_dots[1024];   // 4 KB
    __shared__ char  s_bfr[9216];    // 64 lanes x 144 B (8 x half8 + 16B pad)
    __shared__ char  s_tab[1536];    // w1/b1 (1024) + b2/w3 (512)
    __shared__ float s_red[8];

    const int tid = threadIdx.x;
    const int bid = blockIdx.x;                  // m*1024 + n1
    const long row_off = (long)bid * 3072;

    // ---- stage diff row + weight tables (coalesced float4) ----
    {
        const float4v* gd = (const float4v*)(diff + row_off);
        float4v* sd = (float4v*)s_diff;
        #pragma unroll
        for (int it = 0; it < 3; ++it) sd[tid + 256 * it] = gd[tid + 256 * it];
        // bfr: global [lane*128 + slot*16] -> LDS [lane*144 + slot*16]
        #pragma unroll
        for (int i = tid; i < 512; i += 256) {
            const int ln = i >> 3, slot = i & 7;
            *(float4v*)(s_bfr + ln * 144 + slot * 16) = ((const float4v*)ws)[i];
        }
        if (tid < 96) ((float4v*)s_tab)[tid] = ((const float4v*)(ws + 8192))[tid];
    }
    __syncthreads();

    const int lane = tid & 63, wv = tid >> 6;
    const int lg = lane >> 4,  lr = lane & 15;

    // W2^T A-fragments from LDS (conflict-free if sunk into the loop)
    const char* fb = s_bfr + lane * 144;
    half8 bfr[4][2];
    #pragma unroll
    for (int nt = 0; nt < 4; ++nt)
        #pragma unroll
        for (int kh = 0; kh < 2; ++kh)
            bfr[nt][kh] = *(const half8*)(fb + nt * 32 + kh * 16);

    const char* tb = s_tab + lg * 256;
    float2v w1p[2][3][4], b1p[2][4];
    #pragma unroll
    for (int kh = 0; kh < 2; ++kh) {
        #pragma unroll
        for (int p = 0; p < 4; ++p) {
            #pragma unroll
            for (int d = 0; d < 3; ++d)
                w1p[kh][d][p] = *(const float2v*)(tb + kh * 96 + d * 32 + p * 8);
            b1p[kh][p] = *(const float2v*)(tb + 192 + kh * 32 + p * 8);
        }
    }
    const char* tc = s_tab + 1024 + lg * 128;
    float4v b2v[4], w3v[4];
    #pragma unroll
    for (int nt = 0; nt < 4; ++nt) {
        b2v[nt] = *(const float4v*)(tc + nt * 16);
        w3v[nt] = *(const float4v*)(tc + 64 + nt * 16);
    }

    const float2v zero2 = {0.0f, 0.0f};
    const float4v zero4 = {0.0f, 0.0f, 0.0f, 0.0f};

    // ---- main loop: 16 tiles of 16 points per wave ----
    const int jw0 = wv * 256;
    for (int t = 0; t < 16; ++t) {
        const int j0 = jw0 + t * 16;
        const int jp = j0 + lr;                 // this lane's point (B-col)
        const float x0 = s_diff[jp * 3 + 0];
        const float x1 = s_diff[jp * 3 + 1];
        const float x2 = s_diff[jp * 3 + 2];
        const float2v x0p = {x0, x0}, x1p = {x1, x1}, x2p = {x2, x2};

        half8 afr[2];
        #pragma unroll
        for (int kh = 0; kh < 2; ++kh) {
            union { fp16x2 h2[4]; half8 h8; } u;
            #pragma unroll
            for (int p = 0; p < 4; ++p) {
                float2v h = b1p[kh][p];
                h = __builtin_elementwise_fma(x0p, w1p[kh][0][p], h);
                h = __builtin_elementwise_fma(x1p, w1p[kh][1][p], h);
                h = __builtin_elementwise_fma(x2p, w1p[kh][2][p], h);
                h = __builtin_elementwise_max(h, zero2);
                u.h2[p] = __builtin_amdgcn_cvt_pkrtz(h[0], h[1]);
            }
            afr[kh] = u.h8;
        }

        float2v sr2 = zero2;
        #pragma unroll
        for (int nt = 0; nt < 4; ++nt) {
            float4v acc = b2v[nt];                             // bias via C-in
            acc = MFMA_F16(bfr[nt][0], afr[0], acc, 0, 0, 0);  // A=W2^T, B=h1
            acc = MFMA_F16(bfr[nt][1], afr[1], acc, 0, 0, 0);
            const float4v rl = __builtin_elementwise_max(acc, zero4);
            const float2v rlo = {rl[0], rl[1]}, rhi = {rl[2], rl[3]};
            const float2v wlo = {w3v[nt][0], w3v[nt][1]};
            const float2v whi = {w3v[nt][2], w3v[nt][3]};
            sr2 = __builtin_elementwise_fma(rlo, wlo, sr2);
            sr2 = __builtin_elementwise_fma(rhi, whi, sr2);
        }
        float sr = sr2[0] + sr2[1];
        sr += __shfl_xor(sr, 16, 64);
        sr += __shfl_xor(sr, 32, 64);
        if (lane < 16) s_dots[j0 + lane] = sr;
    }
    __syncthreads();

    // ---- masked softmax over the 1024 points (block-wide, tid*4) ----
    const int j4 = tid * 4;
    float4v dv = *(const float4v*)&s_dots[j4];
    const int4 mv = *(const int4*)(mask + (long)bid * 1024 + j4);
    const float NINF = -__builtin_inff();
    float d0 = mv.x ? NINF : dv[0];
    float d1 = mv.y ? NINF : dv[1];
    float d2 = mv.z ? NINF : dv[2];
    float d3 = mv.w ? NINF : dv[3];

    float mx = fmaxf(fmaxf(d0, d1), fmaxf(d2, d3));
    #pragma unroll
    for (int off = 1; off < 64; off <<= 1) mx = fmaxf(mx, __shfl_xor(mx, off, 64));
    if (lane == 0) s_red[wv] = mx;
    __syncthreads();
    mx = fmaxf(fmaxf(s_red[0], s_red[1]), fmaxf(s_red[2], s_red[3]));

    const float e0 = mv.x ? 0.0f : __expf(d0 - mx);
    const float e1 = mv.y ? 0.0f : __expf(d1 - mx);
    const float e2 = mv.z ? 0.0f : __expf(d2 - mx);
    const float e3 = mv.w ? 0.0f : __expf(d3 - mx);
    float s = (e0 + e1) + (e2 + e3);
    #pragma unroll
    for (int off = 1; off < 64; off <<= 1) s += __shfl_xor(s, off, 64);
    if (lane == 0) s_red[4 + wv] = s;
    __syncthreads();
    const float tot = (s_red[4] + s_red[5]) + (s_red[6] + s_red[7]);
    const float inv = 1.0f / tot;

    float4v ov = {e0 * inv, e1 * inv, e2 * inv, e3 * inv};
    *(float4v*)(out + (long)bid * 1024 + j4) = ov;
}

extern "C" void kernel_launch(void* const* d_in, const int* in_sizes, int n_in,
                              void* d_out, int out_size, void* d_ws, size_t ws_size,
                              hipStream_t stream) {
    const float* diff = (const float*)d_in[0];
    const int*   mask = (const int*)d_in[1];
    const float* W1   = (const float*)d_in[2];
    const float* b1   = (const float*)d_in[3];
    const float* W2   = (const float*)d_in[4];
    const float* b2   = (const float*)d_in[5];
    const float* W3   = (const float*)d_in[6];
    // b3 (d_in[7]) cancels in softmax -> unused
    float* out = (float*)d_out;
    char*  ws  = (char*)d_ws;   // needs ~9.7 KB

    prepack_kernel<<<dim3(1), dim3(64), 0, stream>>>(W1, b1, W2, b2, W3, ws);
    mlp_softmax_kernel<<<dim3(4096), dim3(256), 0, stream>>>(diff, mask, ws, out);
}